// Round 6
// baseline (204.993 us; speedup 1.0000x reference)
//
#include <hip/hip_runtime.h>
#include <hip/hip_bf16.h>

typedef __attribute__((ext_vector_type(4))) float  f32x4;
typedef __attribute__((ext_vector_type(4))) float  float4v;
typedef __attribute__((ext_vector_type(8))) short  bf16x8;
typedef __attribute__((ext_vector_type(4))) short  bf16x4;

#define LDT     72      // padded LDS row stride (bf16 units) = 144 B
#define XSTR_B  65536   // 32*32*64
#define XSTR_H  2048    // 32*64
#define XSTR_W  64
#define WSTR_P  36864   // 576*64
#define OSTR_B  57600   // 30*30*64

__device__ __forceinline__ short f2bf(float f) {
  union { float f; unsigned u; } v; v.f = f;
  unsigned r = v.u + 0x7fffu + ((v.u >> 16) & 1u);  // RNE
  return (short)(r >> 16);
}

__global__ __launch_bounds__(256, 2)   // 256-VGPR cap: depth-2 prefetch (64 fp32 regs) must not spill
void lc2d_kernel(const float* __restrict__ x, const float* __restrict__ wgt,
                 const float* __restrict__ bias, float* __restrict__ out) {
  __shared__ short Asm[64 * LDT];   // A[b][k]  (patches, bf16)
  __shared__ short Wsm[64 * LDT];   // W^T[o][k] (weights, bf16)

  // bijective XCD swizzle: nwg=900, 8 XCDs, q=112, rr=4
  int orig = blockIdx.x;
  int xcd  = orig & 7;
  int idx  = orig >> 3;
  int p = (xcd < 4 ? xcd * 113 : 4 * 113 + (xcd - 4) * 112) + idx;
  int r = p / 30;
  int c = p - r * 30;

  int tid  = threadIdx.x;
  int lane = tid & 63;
  int wid  = tid >> 6;
  int wr   = (wid >> 1) * 32;   // wave's batch-row offset
  int wc   = (wid & 1) * 32;    // wave's filter-col offset
  int l16  = lane & 15;
  int lhi  = lane >> 4;

  // A staging coords: thread owns float4 at (row = it*16 + tid>>4, k = ac4..ac4+3)
  int ac4   = (tid & 15) * 4;
  int arow0 = tid >> 4;

  const float* xbase = x + (r * XSTR_H + c * XSTR_W);
  const float* wbase = wgt + p * WSTR_P;

  // depth-2 ping-pong prefetch buffers (indices are compile-time after full unroll)
  float4v av[2][4];
  float   wv[2][16];

  f32x4 acc[2][2] = {{{0.f,0.f,0.f,0.f},{0.f,0.f,0.f,0.f}},
                     {{0.f,0.f,0.f,0.f},{0.f,0.f,0.f,0.f}}};

  // hoist bias loads: overlap with the K-loop
  const float* bb = bias + (r * 30 + c) * 64;
  float bv0 = bb[wc + l16];
  float bv1 = bb[wc + 16 + l16];

  // chunk t covers f = t*64 .. t*64+63 ; di = t/3, dj = t%3 (compile-time after unroll)
  auto issue_loads = [&](int t, int pb) {
    int di = t / 3, dj = t - di * 3;
    const float* xa = xbase + di * XSTR_H + dj * XSTR_W + ac4;
#pragma unroll
    for (int it = 0; it < 4; ++it) {
      int b = it * 16 + arow0;
      av[pb][it] = *(const float4v*)(xa + (long)b * XSTR_B);   // x: temporal (tap reuse via L2/L3)
    }
    // W: use-once stream -> non-temporal (don't pollute caches)
    const float* wa = wbase + (t * 64 + wid * 16) * 64 + lane;
#pragma unroll
    for (int i = 0; i < 16; ++i) wv[pb][i] = __builtin_nontemporal_load(wa + i * 64);
  };

  issue_loads(0, 0);
  issue_loads(1, 1);

#pragma unroll
  for (int t = 0; t < 9; ++t) {
    const int pb = t & 1;
    __syncthreads();                 // previous chunk's LDS reads done
    // ---- stage A: bf16x4 writes, row b, cols ac4..ac4+3  (waits only on chunk-t loads,
    //      issued ~2 iterations ago -> latency already covered)
#pragma unroll
    for (int it = 0; it < 4; ++it) {
      int b = it * 16 + arow0;
      bf16x4 w4 = { f2bf(av[pb][it].x), f2bf(av[pb][it].y), f2bf(av[pb][it].z), f2bf(av[pb][it].w) };
      *(bf16x4*)&Asm[b * LDT + ac4] = w4;
    }
    // ---- stage W transposed: lane holds W[f = t*64+wid*16+i][o = lane] -> Wsm[o][k]
    {
      bf16x8 lo, hi;
#pragma unroll
      for (int i = 0; i < 8; ++i) { lo[i] = f2bf(wv[pb][i]); hi[i] = f2bf(wv[pb][8 + i]); }
      *(bf16x8*)&Wsm[lane * LDT + wid * 16]     = lo;
      *(bf16x8*)&Wsm[lane * LDT + wid * 16 + 8] = hi;
    }
    if (t < 7) issue_loads(t + 2, pb);   // refill the bank just consumed; waited on ~2 iters later
    __syncthreads();
    // ---- compute: 2 k-steps of 32, 2x2 fragments
#pragma unroll
    for (int s = 0; s < 2; ++s) {
      int kb = s * 32 + lhi * 8;
      bf16x8 a0 = *(const bf16x8*)&Asm[(wr +  0 + l16) * LDT + kb];
      bf16x8 a1 = *(const bf16x8*)&Asm[(wr + 16 + l16) * LDT + kb];
      bf16x8 b0 = *(const bf16x8*)&Wsm[(wc +  0 + l16) * LDT + kb];
      bf16x8 b1 = *(const bf16x8*)&Wsm[(wc + 16 + l16) * LDT + kb];
      acc[0][0] = __builtin_amdgcn_mfma_f32_16x16x32_bf16(a0, b0, acc[0][0], 0, 0, 0);
      acc[0][1] = __builtin_amdgcn_mfma_f32_16x16x32_bf16(a0, b1, acc[0][1], 0, 0, 0);
      acc[1][0] = __builtin_amdgcn_mfma_f32_16x16x32_bf16(a1, b0, acc[1][0], 0, 0, 0);
      acc[1][1] = __builtin_amdgcn_mfma_f32_16x16x32_bf16(a1, b1, acc[1][1], 0, 0, 0);
    }
  }

  // ---- epilogue: bias + relu + NT store (D layout: col = lane&15, row = (lane>>4)*4 + reg)
  float* ob = out + (r * 30 + c) * 64;
#pragma unroll
  for (int m = 0; m < 2; ++m) {
#pragma unroll
    for (int j = 0; j < 4; ++j) {
      int b = wr + m * 16 + lhi * 4 + j;
#pragma unroll
      for (int n = 0; n < 2; ++n) {
        float v = acc[m][n][j] + (n ? bv1 : bv0);
        __builtin_nontemporal_store(fmaxf(v, 0.f), &ob[(long)b * OSTR_B + wc + n * 16 + l16]);
      }
    }
  }
}

extern "C" void kernel_launch(void* const* d_in, const int* in_sizes, int n_in,
                              void* d_out, int out_size, void* d_ws, size_t ws_size,
                              hipStream_t stream) {
  const float* x    = (const float*)d_in[0];
  const float* wgt  = (const float*)d_in[1];
  const float* bias = (const float*)d_in[2];
  float* out = (float*)d_out;
  hipLaunchKernelGGL(lc2d_kernel, dim3(900), dim3(256), 0, stream, x, wgt, bias, out);
}

// Round 7
// 204.337 us; speedup vs baseline: 1.0032x; 1.0032x over previous
//
#include <hip/hip_runtime.h>
#include <hip/hip_bf16.h>

typedef __attribute__((ext_vector_type(4))) float  f32x4;
typedef __attribute__((ext_vector_type(4))) float  float4v;
typedef __attribute__((ext_vector_type(8))) short  bf16x8;
typedef __attribute__((ext_vector_type(4))) short  bf16x4;

#define LDT     72      // padded LDS row stride (bf16 units) = 144 B
#define XSTR_B  65536   // 32*32*64
#define XSTR_H  2048    // 32*64
#define XSTR_W  64
#define WSTR_P  36864   // 576*64
#define OSTR_B  57600   // 30*30*64

__device__ __forceinline__ short f2bf(float f) {
  union { float f; unsigned u; } v; v.f = f;
  unsigned r = v.u + 0x7fffu + ((v.u >> 16) & 1u);  // RNE
  return (short)(r >> 16);
}

// Raw barrier WITHOUT the __syncthreads() vmcnt(0) drain: LDS ops are ordered by
// lgkmcnt(0); in-flight global loads (register-destined, no cross-wave hazard)
// stay outstanding across the barrier. asm "memory" fences stop LLVM migrating
// ds ops across the barrier.
__device__ __forceinline__ void wg_barrier_keep_vmcnt() {
  asm volatile("s_waitcnt lgkmcnt(0)" ::: "memory");
  __builtin_amdgcn_s_barrier();
  asm volatile("" ::: "memory");
}

__global__ __launch_bounds__(256, 2)   // 256-VGPR cap: depth-2 prefetch (64 fp32 regs) must not spill
void lc2d_kernel(const float* __restrict__ x, const float* __restrict__ wgt,
                 const float* __restrict__ bias, float* __restrict__ out) {
  __shared__ short Asm[64 * LDT];   // A[b][k]  (patches, bf16)
  __shared__ short Wsm[64 * LDT];   // W^T[o][k] (weights, bf16)

  // bijective XCD swizzle: nwg=900, 8 XCDs, q=112, rr=4
  int orig = blockIdx.x;
  int xcd  = orig & 7;
  int idx  = orig >> 3;
  int p = (xcd < 4 ? xcd * 113 : 4 * 113 + (xcd - 4) * 112) + idx;
  int r = p / 30;
  int c = p - r * 30;

  int tid  = threadIdx.x;
  int lane = tid & 63;
  int wid  = tid >> 6;
  int wr   = (wid >> 1) * 32;   // wave's batch-row offset
  int wc   = (wid & 1) * 32;    // wave's filter-col offset
  int l16  = lane & 15;
  int lhi  = lane >> 4;

  // A staging coords: thread owns float4 at (row = it*16 + tid>>4, k = ac4..ac4+3)
  int ac4   = (tid & 15) * 4;
  int arow0 = tid >> 4;

  const float* xbase = x + (r * XSTR_H + c * XSTR_W);
  const float* wbase = wgt + p * WSTR_P;

  // depth-2 ping-pong prefetch buffers (indices compile-time after full unroll)
  float4v av[2][4];
  float   wv[2][16];

  f32x4 acc[2][2] = {{{0.f,0.f,0.f,0.f},{0.f,0.f,0.f,0.f}},
                     {{0.f,0.f,0.f,0.f},{0.f,0.f,0.f,0.f}}};

  // hoist bias loads: overlap with the K-loop
  const float* bb = bias + (r * 30 + c) * 64;
  float bv0 = bb[wc + l16];
  float bv1 = bb[wc + 16 + l16];

  // chunk t covers f = t*64 .. t*64+63 ; di = t/3, dj = t%3 (compile-time after unroll)
  auto issue_loads = [&](int t, int pb) {
    int di = t / 3, dj = t - di * 3;
    const float* xa = xbase + di * XSTR_H + dj * XSTR_W + ac4;
#pragma unroll
    for (int it = 0; it < 4; ++it) {
      int b = it * 16 + arow0;
      av[pb][it] = *(const float4v*)(xa + (long)b * XSTR_B);   // x: temporal (tap reuse via L2/L3)
    }
    // W: use-once stream -> non-temporal (don't pollute caches)
    const float* wa = wbase + (t * 64 + wid * 16) * 64 + lane;
#pragma unroll
    for (int i = 0; i < 16; ++i) wv[pb][i] = __builtin_nontemporal_load(wa + i * 64);
  };

  issue_loads(0, 0);
  issue_loads(1, 1);

#pragma unroll
  for (int t = 0; t < 9; ++t) {
    const int pb = t & 1;
    wg_barrier_keep_vmcnt();         // previous chunk's LDS reads done; loads stay in flight
    // ---- stage A: compiler emits counted vmcnt for chunk-t regs (t+1's loads stay outstanding)
#pragma unroll
    for (int it = 0; it < 4; ++it) {
      int b = it * 16 + arow0;
      bf16x4 w4 = { f2bf(av[pb][it].x), f2bf(av[pb][it].y), f2bf(av[pb][it].z), f2bf(av[pb][it].w) };
      *(bf16x4*)&Asm[b * LDT + ac4] = w4;
    }
    // ---- stage W transposed: lane holds W[f = t*64+wid*16+i][o = lane] -> Wsm[o][k]
    {
      bf16x8 lo, hi;
#pragma unroll
      for (int i = 0; i < 8; ++i) { lo[i] = f2bf(wv[pb][i]); hi[i] = f2bf(wv[pb][8 + i]); }
      *(bf16x8*)&Wsm[lane * LDT + wid * 16]     = lo;
      *(bf16x8*)&Wsm[lane * LDT + wid * 16 + 8] = hi;
    }
    if (t < 7) issue_loads(t + 2, pb);   // refill consumed bank; now survives the barrier below
    wg_barrier_keep_vmcnt();
    // ---- compute: 2 k-steps of 32, 2x2 fragments
#pragma unroll
    for (int s = 0; s < 2; ++s) {
      int kb = s * 32 + lhi * 8;
      bf16x8 a0 = *(const bf16x8*)&Asm[(wr +  0 + l16) * LDT + kb];
      bf16x8 a1 = *(const bf16x8*)&Asm[(wr + 16 + l16) * LDT + kb];
      bf16x8 b0 = *(const bf16x8*)&Wsm[(wc +  0 + l16) * LDT + kb];
      bf16x8 b1 = *(const bf16x8*)&Wsm[(wc + 16 + l16) * LDT + kb];
      acc[0][0] = __builtin_amdgcn_mfma_f32_16x16x32_bf16(a0, b0, acc[0][0], 0, 0, 0);
      acc[0][1] = __builtin_amdgcn_mfma_f32_16x16x32_bf16(a0, b1, acc[0][1], 0, 0, 0);
      acc[1][0] = __builtin_amdgcn_mfma_f32_16x16x32_bf16(a1, b0, acc[1][0], 0, 0, 0);
      acc[1][1] = __builtin_amdgcn_mfma_f32_16x16x32_bf16(a1, b1, acc[1][1], 0, 0, 0);
    }
  }

  // ---- epilogue: bias + relu + NT store (D layout: col = lane&15, row = (lane>>4)*4 + reg)
  float* ob = out + (r * 30 + c) * 64;
#pragma unroll
  for (int m = 0; m < 2; ++m) {
#pragma unroll
    for (int j = 0; j < 4; ++j) {
      int b = wr + m * 16 + lhi * 4 + j;
#pragma unroll
      for (int n = 0; n < 2; ++n) {
        float v = acc[m][n][j] + (n ? bv1 : bv0);
        __builtin_nontemporal_store(fmaxf(v, 0.f), &ob[(long)b * OSTR_B + wc + n * 16 + l16]);
      }
    }
  }
}

extern "C" void kernel_launch(void* const* d_in, const int* in_sizes, int n_in,
                              void* d_out, int out_size, void* d_ws, size_t ws_size,
                              hipStream_t stream) {
  const float* x    = (const float*)d_in[0];
  const float* wgt  = (const float*)d_in[1];
  const float* bias = (const float*)d_in[2];
  float* out = (float*)d_out;
  hipLaunchKernelGGL(lc2d_kernel, dim3(900), dim3(256), 0, stream, x, wgt, bias, out);
}